// Round 9
// baseline (436.878 us; speedup 1.0000x reference)
//
#include <hip/hip_runtime.h>
#include <hip/hip_fp16.h>

// ---------------------------------------------------------------------------
// GCN forward, source-bucketed-CSR, fp16 gather payload, radix-binned build.
//   CSR build: bin edges by dest-partition into compact staging (packed u32),
//   then partition-local hist + scatter (all slices L2-resident).
//   per layer: H(fp16) = (relu?)(X) @ W * dinv[row]       (gemm_tile_kernel)
//              X[c] = b + dinv[c]*(sum_q sum_{r in bkt q} H[r] + H[c])
// ---------------------------------------------------------------------------

#define NBKT 8
#define CAP  262144   // per-partition staging cap; E/8=200k avg, 143 sigma margin

__global__ __launch_bounds__(256) void zero_i32_kernel(int* __restrict__ p, int n) {
    int i = blockIdx.x * blockDim.x + threadIdx.x;
    if (i < n) p[i] = 0;
}

// Pass A: bin edges by dest partition. LDS count -> block bulk-reserve ->
// append packed (r<<14 | c-lo) to stag[part]. Append-contiguous writes.
__global__ __launch_bounds__(256) void bin_kernel(const int* __restrict__ row,
                                                  const int* __restrict__ col,
                                                  int* __restrict__ pcnt,
                                                  unsigned* __restrict__ stag,
                                                  int E, int span) {
    __shared__ int scnt[NBKT];
    __shared__ int gbase[NBKT];
    const int tid = threadIdx.x;
    for (int base = blockIdx.x * 1024; base < E; base += gridDim.x * 1024) {
        if (tid < NBKT) scnt[tid] = 0;
        __syncthreads();
        int e0 = base + tid * 4;
        unsigned pk[4]; int pt[4], lp[4];
        if (e0 + 4 <= E) {
            int4 r4 = *(const int4*)(row + e0);
            int4 c4 = *(const int4*)(col + e0);
            int rr[4] = {r4.x, r4.y, r4.z, r4.w};
            int cc[4] = {c4.x, c4.y, c4.z, c4.w};
#pragma unroll
            for (int u = 0; u < 4; ++u) {
                int p = cc[u] / span;
                pt[u] = p;
                pk[u] = ((unsigned)rr[u] << 14) | (unsigned)(cc[u] - p * span);
                lp[u] = atomicAdd(&scnt[p], 1);
            }
        } else {
#pragma unroll
            for (int u = 0; u < 4; ++u) {
                int e = e0 + u;
                if (e < E) {
                    int r = row[e], c = col[e];
                    int p = c / span;
                    pt[u] = p;
                    pk[u] = ((unsigned)r << 14) | (unsigned)(c - p * span);
                    lp[u] = atomicAdd(&scnt[p], 1);
                } else pt[u] = -1;
            }
        }
        __syncthreads();
        if (tid < NBKT) gbase[tid] = atomicAdd(&pcnt[tid], scnt[tid]);
        __syncthreads();
#pragma unroll
        for (int u = 0; u < 4; ++u) {
            if (e0 + u < E) {
                stag[(size_t)pt[u] * CAP + (unsigned)(gbase[pt[u]] + lp[u])] = pk[u];
            }
        }
        __syncthreads();
    }
}

// Pass B: partition-local histogram from compact staging.
__global__ __launch_bounds__(256) void hist3_kernel(const unsigned* __restrict__ stag,
                                                    const int* __restrict__ pcnt,
                                                    int* __restrict__ cnt2, int span) {
    const int part = blockIdx.x & 7;
    const int n = pcnt[part];
    const unsigned* s = stag + (size_t)part * CAP;
    const int lo = part * span;
    const int stride = (gridDim.x >> 3) * 256;
    for (int i = (blockIdx.x >> 3) * 256 + threadIdx.x; i < n; i += stride) {
        unsigned v = s[i];
        int r = v >> 14;
        int c = lo + (v & 0x3FFF);
        atomicAdd(&cnt2[(size_t)c * NBKT + r / span], 1);
    }
}

// Pass C: partition-local scatter from compact staging into eidx.
__global__ __launch_bounds__(256) void scatter3_kernel(const unsigned* __restrict__ stag,
                                                       const int* __restrict__ pcnt,
                                                       int* __restrict__ cursor,
                                                       int* __restrict__ eidx, int span) {
    const int part = blockIdx.x & 7;
    const int n = pcnt[part];
    const unsigned* s = stag + (size_t)part * CAP;
    const int lo = part * span;
    const int stride = (gridDim.x >> 3) * 256;
    for (int i = (blockIdx.x >> 3) * 256 + threadIdx.x; i < n; i += stride) {
        unsigned v = s[i];
        int r = v >> 14;
        int c = lo + (v & 0x3FFF);
        int pos = atomicAdd(&cursor[(size_t)c * NBKT + r / span], 1);
        eidx[pos] = r;
    }
}

__global__ __launch_bounds__(256) void dinv2_kernel(const int* __restrict__ offs2,
                                                    float* __restrict__ dinv, int N) {
    int i = blockIdx.x * blockDim.x + threadIdx.x;
    if (i < N) {
        int deg = offs2[i * NBKT + NBKT] - offs2[i * NBKT];
        dinv[i] = rsqrtf((float)deg + 1.0f);  // +1 self-loop
    }
}

__global__ __launch_bounds__(256) void block_reduce_kernel(const int* __restrict__ cnt,
                                                           int* __restrict__ bsum, int n) {
    __shared__ int s[256];
    int i = blockIdx.x * 256 + threadIdx.x;
    s[threadIdx.x] = (i < n) ? cnt[i] : 0;
    __syncthreads();
    for (int off = 128; off > 0; off >>= 1) {
        if (threadIdx.x < off) s[threadIdx.x] += s[threadIdx.x + off];
        __syncthreads();
    }
    if (threadIdx.x == 0) bsum[blockIdx.x] = s[0];
}

// single block, exclusive-scans bsum[nb] in place, any nb (chunks of 512)
__global__ __launch_bounds__(512) void scan_bsums_big_kernel(int* __restrict__ bsum, int nb) {
    __shared__ int s[512];
    int tid = threadIdx.x;
    int run = 0;
    for (int start = 0; start < nb; start += 512) {
        int i = start + tid;
        int v = (i < nb) ? bsum[i] : 0;
        s[tid] = v;
        __syncthreads();
        for (int off = 1; off < 512; off <<= 1) {
            int t = (tid >= off) ? s[tid - off] : 0;
            __syncthreads();
            s[tid] += t;
            __syncthreads();
        }
        if (i < nb) bsum[i] = s[tid] - v + run;  // exclusive + carry
        int tot = s[511];
        __syncthreads();
        run += tot;
    }
}

__global__ __launch_bounds__(256) void scan_kernel(const int* __restrict__ cnt,
                                                   const int* __restrict__ bsum,
                                                   int* __restrict__ offs, int n) {
    __shared__ int s[256];
    int i = blockIdx.x * 256 + threadIdx.x;
    int v = (i < n) ? cnt[i] : 0;
    s[threadIdx.x] = v;
    __syncthreads();
    for (int off = 1; off < 256; off <<= 1) {
        int t = (threadIdx.x >= off) ? s[threadIdx.x - off] : 0;
        __syncthreads();
        s[threadIdx.x] += t;
        __syncthreads();
    }
    int excl = s[threadIdx.x] - v + bsum[blockIdx.x];
    if (i < n) offs[i] = excl;
    if (i == n - 1) offs[n] = excl + v;
}

__global__ __launch_bounds__(256) void copy_i32_kernel(const int* __restrict__ src,
                                                       int* __restrict__ dst, int n) {
    int i = blockIdx.x * blockDim.x + threadIdx.x;
    if (i < n) dst[i] = src[i];
}

// H(fp16) = ((RELU? relu(in) : in) @ W) * dinv[row].  W is [F_IN,F_OUT] rowmaj.
template <int F_IN, int F_OUT, bool RELU>
__global__ __launch_bounds__(256, 4) void gemm_tile_kernel(const float* __restrict__ in,
                                                           const float* __restrict__ W,
                                                           const float* __restrict__ dinv,
                                                           ushort* __restrict__ outh, int N) {
    constexpr int TC   = F_OUT / 4;   // col-thread groups (16 or 8)
    constexpr int TR   = 256 / TC;    // row-thread groups (16 or 32)
    constexpr int ROWS = TR * 4;      // rows per block (64 or 128)
    constexpr int NKB  = F_IN / 64;   // k-blocks of 64
    __shared__ float sIn[ROWS][68];
    __shared__ float sW[64][F_OUT];

    const int tc = threadIdx.x % TC;
    const int tr = threadIdx.x / TC;
    const int r0 = blockIdx.x * ROWS;

    float acc[4][4] = {};

#pragma unroll
    for (int kb = 0; kb < NKB; ++kb) {
        if (kb) __syncthreads();
        for (int idx = threadIdx.x; idx < ROWS * 16; idx += 256) {
            int rr = idx / 16, c4 = (idx % 16) * 4;
            int gr = min(r0 + rr, N - 1);
            float4 v = *(const float4*)&in[(size_t)gr * F_IN + kb * 64 + c4];
            if (RELU) {
                v.x = fmaxf(v.x, 0.f); v.y = fmaxf(v.y, 0.f);
                v.z = fmaxf(v.z, 0.f); v.w = fmaxf(v.w, 0.f);
            }
            *(float4*)&sIn[rr][c4] = v;
        }
        for (int idx = threadIdx.x; idx < 64 * F_OUT / 4; idx += 256) {
            int kr = idx / (F_OUT / 4), c4 = (idx % (F_OUT / 4)) * 4;
            *(float4*)&sW[kr][c4] = *(const float4*)&W[(size_t)(kb * 64 + kr) * F_OUT + c4];
        }
        __syncthreads();
#pragma unroll 2
        for (int kk = 0; kk < 64; kk += 4) {
            float4 iv[4], wv[4];
#pragma unroll
            for (int i = 0; i < 4; ++i) iv[i] = *(const float4*)&sIn[tr * 4 + i][kk];
#pragma unroll
            for (int q = 0; q < 4; ++q) wv[q] = *(const float4*)&sW[kk + q][tc * 4];
#pragma unroll
            for (int i = 0; i < 4; ++i) {
                const float ik[4] = {iv[i].x, iv[i].y, iv[i].z, iv[i].w};
#pragma unroll
                for (int q = 0; q < 4; ++q) {
                    acc[i][0] = fmaf(ik[q], wv[q].x, acc[i][0]);
                    acc[i][1] = fmaf(ik[q], wv[q].y, acc[i][1]);
                    acc[i][2] = fmaf(ik[q], wv[q].z, acc[i][2]);
                    acc[i][3] = fmaf(ik[q], wv[q].w, acc[i][3]);
                }
            }
        }
    }
#pragma unroll
    for (int i = 0; i < 4; ++i) {
        int r = r0 + tr * 4 + i;
        if (r < N) {
            float d = dinv[r];
            ushort4 v;
            v.x = __half_as_ushort(__float2half(acc[i][0] * d));
            v.y = __half_as_ushort(__float2half(acc[i][1] * d));
            v.z = __half_as_ushort(__float2half(acc[i][2] * d));
            v.w = __half_as_ushort(__float2half(acc[i][3] * d));
            *(ushort4*)&outh[(size_t)r * F_OUT + tc * 4] = v;
        }
    }
}

__device__ inline void h8acc(float* acc, uint4 u) {
    const __half2* p = (const __half2*)&u;
#pragma unroll
    for (int i = 0; i < 4; ++i) {
        float2 f = __half22float2(p[i]);
        acc[2 * i]     += f.x;
        acc[2 * i + 1] += f.y;
    }
}

// out[c, jw*8..+7] = b + dinv[c]*( sum_{neighbors} H16[r] + H16[c] )
// F/8 lanes per destination node; each lane gathers 16 B = 8 fp16 features.
template <int F>
__global__ __launch_bounds__(256) void agg_half_kernel(const ushort* __restrict__ h,
                                                       const int* __restrict__ offs2,
                                                       const int* __restrict__ eidx,
                                                       const float* __restrict__ dinv,
                                                       const float* __restrict__ b,
                                                       float* __restrict__ out, int N) {
    constexpr int L = F / 8;  // lanes per node (8 or 4), also uint4s per row
    int tid = blockIdx.x * 256 + threadIdx.x;
    int seg = tid / L;
    int jw  = tid % L;
    if (seg >= N) return;
    const uint4* hv = (const uint4*)h;

    float a0[8] = {}, a1[8] = {};
    const int base = seg * NBKT;
    int ks = offs2[base];
#pragma unroll
    for (int q = 0; q < NBKT; ++q) {
        int ke = offs2[base + q + 1];
        int k = ks;
        for (; k + 2 <= ke; k += 2) {
            int r0 = eidx[k], r1 = eidx[k + 1];
            h8acc(a0, hv[(size_t)r0 * L + jw]);
            h8acc(a1, hv[(size_t)r1 * L + jw]);
        }
        if (k < ke) h8acc(a0, hv[(size_t)eidx[k] * L + jw]);
        ks = ke;
    }
    h8acc(a0, hv[(size_t)seg * L + jw]);  // self-loop
#pragma unroll
    for (int i = 0; i < 8; ++i) a0[i] += a1[i];

    float  d  = dinv[seg];
    float4 b0 = *(const float4*)&b[jw * 8];
    float4 b1 = *(const float4*)&b[jw * 8 + 4];
    float4 o0 = {b0.x + d * a0[0], b0.y + d * a0[1], b0.z + d * a0[2], b0.w + d * a0[3]};
    float4 o1 = {b1.x + d * a0[4], b1.y + d * a0[5], b1.z + d * a0[6], b1.w + d * a0[7]};
    *(float4*)&out[(size_t)seg * F + jw * 8]     = o0;
    *(float4*)&out[(size_t)seg * F + jw * 8 + 4] = o1;
}

extern "C" void kernel_launch(void* const* d_in, const int* in_sizes, int n_in,
                              void* d_out, int out_size, void* d_ws, size_t ws_size,
                              hipStream_t stream) {
    const float* x  = (const float*)d_in[0];
    const int*   ei = (const int*)d_in[1];
    const float* W1 = (const float*)d_in[2];
    const float* b1 = (const float*)d_in[3];
    const float* W2 = (const float*)d_in[4];
    const float* b2 = (const float*)d_in[5];
    const float* W3 = (const float*)d_in[6];
    const float* b3 = (const float*)d_in[7];
    const float* W4 = (const float*)d_in[8];
    const float* b4 = (const float*)d_in[9];

    const int N = in_sizes[0] / 128;  // 100000
    const int E = in_sizes[1] / 2;    // 1600000
    const int* row = ei;              // source
    const int* col = ei + E;          // destination
    const int n2 = N * NBKT;
    const int span = (N + NBKT - 1) / NBKT;  // 12500

    // ---- workspace layout (aliased to fit) ----------------------------------
    // persistent: offs2, dinv, eidx, stag, X(f32), H(fp16)
    // transient:  cnt2+pcnt -> alias X (dead after scan / scatter3);
    //             cursor -> aliases H (dead after scatter3, H written later);
    //             bsum -> aliases eidx (dead after scan, eidx written later)
    char* w = (char*)d_ws;
    int*      offs2 = (int*)w;               w += (size_t)(n2 + 4) * 4;   // 16B-pad
    float*    dinv  = (float*)w;             w += (size_t)N * 4;
    int*      eidx  = (int*)w;               w += (size_t)E * 4;
    unsigned* stag  = (unsigned*)w;          w += (size_t)NBKT * CAP * 4; // 8.4 MB
    float*    X     = (float*)w;             w += (size_t)N * 64 * 4;
    ushort*   H     = (ushort*)w;            // N*64 fp16 = 12.8 MB
    int*      cnt2   = (int*)X;
    int*      pcnt   = cnt2 + n2;            // 8 ints, zeroed with cnt2
    int*      cursor = (int*)H;
    int*      bsum   = eidx;
    float*    out    = (float*)d_out;

    const int T   = 256;
    const int NB  = (N + T - 1) / T;        // 391
    const int NB2 = (n2 + T - 1) / T;       // 3125

    // ---- radix-binned CSR build + norm --------------------------------------
    zero_i32_kernel<<<(n2 + NBKT + T - 1) / T, T, 0, stream>>>(cnt2, n2 + NBKT);
    bin_kernel<<<1024, T, 0, stream>>>(row, col, pcnt, stag, E, span);
    hist3_kernel<<<2048, T, 0, stream>>>(stag, pcnt, cnt2, span);
    block_reduce_kernel<<<NB2, T, 0, stream>>>(cnt2, bsum, n2);
    scan_bsums_big_kernel<<<1, 512, 0, stream>>>(bsum, NB2);
    scan_kernel<<<NB2, T, 0, stream>>>(cnt2, bsum, offs2, n2);
    dinv2_kernel<<<NB, T, 0, stream>>>(offs2, dinv, N);
    copy_i32_kernel<<<NB2, T, 0, stream>>>(offs2, cursor, n2);
    scatter3_kernel<<<2048, T, 0, stream>>>(stag, pcnt, cursor, eidx, span);

    const int g64 = (N + 63) / 64;    // gemm blocks, 64 rows/block (F_OUT=64)
    const int g32 = (N + 127) / 128;  // gemm blocks, 128 rows/block (F_OUT=32)
    const int a64 = (N * 8 + T - 1) / T;   // agg blocks, 8 lanes/node
    const int a32 = (N * 4 + T - 1) / T;   // agg blocks, 4 lanes/node

    // ---- layer 1: x[128] -> 64 ---------------------------------------------
    gemm_tile_kernel<128, 64, false><<<g64, T, 0, stream>>>(x, W1, dinv, H, N);
    agg_half_kernel<64><<<a64, T, 0, stream>>>(H, offs2, eidx, dinv, b1, X, N);
    // ---- layer 2 ------------------------------------------------------------
    gemm_tile_kernel<64, 64, true><<<g64, T, 0, stream>>>(X, W2, dinv, H, N);
    agg_half_kernel<64><<<a64, T, 0, stream>>>(H, offs2, eidx, dinv, b2, X, N);
    // ---- layer 3 ------------------------------------------------------------
    gemm_tile_kernel<64, 64, true><<<g64, T, 0, stream>>>(X, W3, dinv, H, N);
    agg_half_kernel<64><<<a64, T, 0, stream>>>(H, offs2, eidx, dinv, b3, X, N);
    // ---- layer 4: 64 -> 32, no ReLU, straight to d_out ----------------------
    gemm_tile_kernel<64, 32, true><<<g32, T, 0, stream>>>(X, W4, dinv, H, N);
    agg_half_kernel<32><<<a32, T, 0, stream>>>(H, offs2, eidx, dinv, b4, out, N);
}

// Round 10
// 312.360 us; speedup vs baseline: 1.3986x; 1.3986x over previous
//
#include <hip/hip_runtime.h>
#include <hip/hip_fp16.h>

// ---------------------------------------------------------------------------
// GCN forward. CSR build = 3-level radix/counting sort with all global writes
// coalesced (round-9: random 4B stores cost ~32B sector writebacks; the fix is
// LDS-assembled, wave-coalesced output).
//   pass1 bin_kernel : edges -> 8 dest-partitions (contiguous appends)
//   pass2 bin2_kernel: partition -> 98 sub-bins of 128 dests (~2k edges each)
//   pass3 sort_sub   : per sub-bin LDS counting sort -> offs2 + eidx coalesced
// per layer: H(fp16) = (relu?)(X) @ W * dinv[row]      (gemm_tile_kernel)
//            X[c] = b + dinv[c]*(sum_bkts sum H16[r] + H16[c])  (agg_half)
// ---------------------------------------------------------------------------

#define NBKT 8
#define CAP  262144   // per-partition staging cap (E/8 = 200k avg)
#define SUBD 128      // dests per sub-bin
#define CAP2 4096     // per-sub-bin cap (mean 2048, sigma ~45)

__global__ __launch_bounds__(256) void zero_i32_kernel(int* __restrict__ p, int n) {
    int i = blockIdx.x * blockDim.x + threadIdx.x;
    if (i < n) p[i] = 0;
}

// Pass 1: bin edges by dest partition. LDS count -> block bulk-reserve ->
// append packed (r<<14 | c-lo) to stag1[part]. Append-contiguous writes.
__global__ __launch_bounds__(256) void bin_kernel(const int* __restrict__ row,
                                                  const int* __restrict__ col,
                                                  int* __restrict__ pcnt,
                                                  unsigned* __restrict__ stag,
                                                  int E, int span) {
    __shared__ int scnt[NBKT];
    __shared__ int gbase[NBKT];
    const int tid = threadIdx.x;
    for (int base = blockIdx.x * 1024; base < E; base += gridDim.x * 1024) {
        if (tid < NBKT) scnt[tid] = 0;
        __syncthreads();
        int e0 = base + tid * 4;
        unsigned pk[4]; int pt[4], lp[4];
        if (e0 + 4 <= E) {
            int4 r4 = *(const int4*)(row + e0);
            int4 c4 = *(const int4*)(col + e0);
            int rr[4] = {r4.x, r4.y, r4.z, r4.w};
            int cc[4] = {c4.x, c4.y, c4.z, c4.w};
#pragma unroll
            for (int u = 0; u < 4; ++u) {
                int p = cc[u] / span;
                pt[u] = p;
                pk[u] = ((unsigned)rr[u] << 14) | (unsigned)(cc[u] - p * span);
                lp[u] = atomicAdd(&scnt[p], 1);
            }
        } else {
#pragma unroll
            for (int u = 0; u < 4; ++u) {
                int e = e0 + u;
                if (e < E) {
                    int r = row[e], c = col[e];
                    int p = c / span;
                    pt[u] = p;
                    pk[u] = ((unsigned)r << 14) | (unsigned)(c - p * span);
                    lp[u] = atomicAdd(&scnt[p], 1);
                } else pt[u] = -1;
            }
        }
        __syncthreads();
        if (tid < NBKT) gbase[tid] = atomicAdd(&pcnt[tid], scnt[tid]);
        __syncthreads();
#pragma unroll
        for (int u = 0; u < 4; ++u) {
            if (e0 + u < E) {
                stag[(size_t)pt[u] * CAP + (unsigned)(gbase[pt[u]] + lp[u])] = pk[u];
            }
        }
        __syncthreads();
    }
}

// Pass 2: within partition, bin by sub-bin (c_local>>7). Repack (r<<7 | c&127).
// Each block handles one 4096-edge tile -> ~40B appends per sub-bin (amp~1.5).
__global__ __launch_bounds__(256) void bin2_kernel(const unsigned* __restrict__ stag1,
                                                   const int* __restrict__ pcnt,
                                                   int* __restrict__ pcnt2,
                                                   unsigned* __restrict__ stag2,
                                                   int nsb) {
    __shared__ int scnt[128];
    __shared__ int gbase[128];
    const int part = blockIdx.x & 7;
    const int n = min(pcnt[part], CAP);
    const unsigned* s = stag1 + (size_t)part * CAP;
    const int t0 = (blockIdx.x >> 3) * 4096;
    if (t0 >= n) return;
    const int tn = min(4096, n - t0);
    const int tid = threadIdx.x;

    for (int i = tid; i < nsb; i += 256) scnt[i] = 0;
    __syncthreads();
    for (int i = tid; i < tn; i += 256) {
        unsigned v = s[t0 + i];
        atomicAdd(&scnt[(v & 0x3FFF) >> 7], 1);
    }
    __syncthreads();
    for (int i = tid; i < nsb; i += 256) {
        gbase[i] = atomicAdd(&pcnt2[part * nsb + i], scnt[i]);
        scnt[i] = 0;
    }
    __syncthreads();
    for (int i = tid; i < tn; i += 256) {
        unsigned v = s[t0 + i];
        int cl = v & 0x3FFF;
        int sb = cl >> 7;
        int lp = atomicAdd(&scnt[sb], 1);
        int pos = min(gbase[sb] + lp, CAP2 - 1);  // clamp (never triggers)
        stag2[(size_t)(part * nsb + sb) * CAP2 + pos] = ((v >> 14) << 7) | (unsigned)(cl & 127);
    }
}

// exclusive scan of src[n] -> dst[n], n <= 1024, single block
__global__ __launch_bounds__(1024) void scan_small_kernel(const int* __restrict__ src,
                                                          int* __restrict__ dst, int n) {
    __shared__ int s[1024];
    int tid = threadIdx.x;
    int v = (tid < n) ? src[tid] : 0;
    s[tid] = v;
    __syncthreads();
    for (int off = 1; off < 1024; off <<= 1) {
        int t = (tid >= off) ? s[tid - off] : 0;
        __syncthreads();
        s[tid] += t;
        __syncthreads();
    }
    if (tid < n) dst[tid] = s[tid] - v;
}

// Pass 3: one workgroup per sub-bin. LDS counting sort over 1024 keys
// (c_local7 * 8 + src_bucket); writes offs2 segment + sorted eidx coalesced.
__global__ __launch_bounds__(256) void sort_sub_kernel(const unsigned* __restrict__ stag2,
                                                       const int* __restrict__ pcnt2,
                                                       const int* __restrict__ sbase,
                                                       int* __restrict__ offs2,
                                                       int* __restrict__ eidx,
                                                       int span, int nsb, int E) {
    __shared__ int cnt[1024];
    __shared__ int tsum[256];
    __shared__ int lout[CAP2];
    const int part = blockIdx.x & 7;
    const int sb   = blockIdx.x >> 3;
    if (sb >= nsb) return;
    const int sbg  = part * nsb + sb;
    const int n    = min(pcnt2[sbg], CAP2);
    const unsigned* s = stag2 + (size_t)sbg * CAP2;
    const int base = sbase[sbg];
    const int c0   = part * span + sb * SUBD;
    const int dd   = min(SUBD, span - sb * SUBD);
    const int tid  = threadIdx.x;

    for (int i = tid; i < 1024; i += 256) cnt[i] = 0;
    __syncthreads();
    for (int i = tid; i < n; i += 256) {
        unsigned v = s[i];
        int r = v >> 7;
        atomicAdd(&cnt[((v & 127) << 3) | (r / span)], 1);
    }
    __syncthreads();
    // exclusive scan of cnt[1024]: 4 per thread + block scan of thread sums
    int a0 = cnt[tid * 4], a1 = cnt[tid * 4 + 1], a2 = cnt[tid * 4 + 2], a3 = cnt[tid * 4 + 3];
    int tot = a0 + a1 + a2 + a3;
    tsum[tid] = tot;
    __syncthreads();
    for (int off = 1; off < 256; off <<= 1) {
        int t = (tid >= off) ? tsum[tid - off] : 0;
        __syncthreads();
        tsum[tid] += t;
        __syncthreads();
    }
    int pre = tsum[tid] - tot;
    cnt[tid * 4]     = pre;
    cnt[tid * 4 + 1] = pre + a0;
    cnt[tid * 4 + 2] = pre + a0 + a1;
    cnt[tid * 4 + 3] = pre + a0 + a1 + a2;
    __syncthreads();
    // coalesced offs2 segment write: offs2[c0*8 + k] = base + excl[k]
    for (int k = tid; k < dd * 8; k += 256) offs2[(size_t)c0 * 8 + k] = base + cnt[k];
    if (part == NBKT - 1 && sb == nsb - 1 && tid == 0) offs2[(size_t)(c0 + dd) * 8] = base + n;
    __syncthreads();
    // LDS scatter (random LDS writes are cheap)
    for (int i = tid; i < n; i += 256) {
        unsigned v = s[i];
        int r = v >> 7;
        int p = atomicAdd(&cnt[((v & 127) << 3) | (r / span)], 1);
        lout[p] = r;
    }
    __syncthreads();
    // coalesced eidx writeout
    for (int i = tid; i < n; i += 256) eidx[base + i] = lout[i];
}

__global__ __launch_bounds__(256) void dinv2_kernel(const int* __restrict__ offs2,
                                                    float* __restrict__ dinv, int N) {
    int i = blockIdx.x * blockDim.x + threadIdx.x;
    if (i < N) {
        int deg = offs2[i * NBKT + NBKT] - offs2[i * NBKT];
        dinv[i] = rsqrtf((float)deg + 1.0f);  // +1 self-loop
    }
}

// H(fp16) = ((RELU? relu(in) : in) @ W) * dinv[row].  W is [F_IN,F_OUT] rowmaj.
template <int F_IN, int F_OUT, bool RELU>
__global__ __launch_bounds__(256, 4) void gemm_tile_kernel(const float* __restrict__ in,
                                                           const float* __restrict__ W,
                                                           const float* __restrict__ dinv,
                                                           ushort* __restrict__ outh, int N) {
    constexpr int TC   = F_OUT / 4;
    constexpr int TR   = 256 / TC;
    constexpr int ROWS = TR * 4;
    constexpr int NKB  = F_IN / 64;
    __shared__ float sIn[ROWS][68];
    __shared__ float sW[64][F_OUT];

    const int tc = threadIdx.x % TC;
    const int tr = threadIdx.x / TC;
    const int r0 = blockIdx.x * ROWS;

    float acc[4][4] = {};

#pragma unroll
    for (int kb = 0; kb < NKB; ++kb) {
        if (kb) __syncthreads();
        for (int idx = threadIdx.x; idx < ROWS * 16; idx += 256) {
            int rr = idx / 16, c4 = (idx % 16) * 4;
            int gr = min(r0 + rr, N - 1);
            float4 v = *(const float4*)&in[(size_t)gr * F_IN + kb * 64 + c4];
            if (RELU) {
                v.x = fmaxf(v.x, 0.f); v.y = fmaxf(v.y, 0.f);
                v.z = fmaxf(v.z, 0.f); v.w = fmaxf(v.w, 0.f);
            }
            *(float4*)&sIn[rr][c4] = v;
        }
        for (int idx = threadIdx.x; idx < 64 * F_OUT / 4; idx += 256) {
            int kr = idx / (F_OUT / 4), c4 = (idx % (F_OUT / 4)) * 4;
            *(float4*)&sW[kr][c4] = *(const float4*)&W[(size_t)(kb * 64 + kr) * F_OUT + c4];
        }
        __syncthreads();
#pragma unroll 2
        for (int kk = 0; kk < 64; kk += 4) {
            float4 iv[4], wv[4];
#pragma unroll
            for (int i = 0; i < 4; ++i) iv[i] = *(const float4*)&sIn[tr * 4 + i][kk];
#pragma unroll
            for (int q = 0; q < 4; ++q) wv[q] = *(const float4*)&sW[kk + q][tc * 4];
#pragma unroll
            for (int i = 0; i < 4; ++i) {
                const float ik[4] = {iv[i].x, iv[i].y, iv[i].z, iv[i].w};
#pragma unroll
                for (int q = 0; q < 4; ++q) {
                    acc[i][0] = fmaf(ik[q], wv[q].x, acc[i][0]);
                    acc[i][1] = fmaf(ik[q], wv[q].y, acc[i][1]);
                    acc[i][2] = fmaf(ik[q], wv[q].z, acc[i][2]);
                    acc[i][3] = fmaf(ik[q], wv[q].w, acc[i][3]);
                }
            }
        }
    }
#pragma unroll
    for (int i = 0; i < 4; ++i) {
        int r = r0 + tr * 4 + i;
        if (r < N) {
            float d = dinv[r];
            ushort4 v;
            v.x = __half_as_ushort(__float2half(acc[i][0] * d));
            v.y = __half_as_ushort(__float2half(acc[i][1] * d));
            v.z = __half_as_ushort(__float2half(acc[i][2] * d));
            v.w = __half_as_ushort(__float2half(acc[i][3] * d));
            *(ushort4*)&outh[(size_t)r * F_OUT + tc * 4] = v;
        }
    }
}

__device__ inline void h8acc(float* acc, uint4 u) {
    const __half2* p = (const __half2*)&u;
#pragma unroll
    for (int i = 0; i < 4; ++i) {
        float2 f = __half22float2(p[i]);
        acc[2 * i]     += f.x;
        acc[2 * i + 1] += f.y;
    }
}

// out[c, jw*8..+7] = b + dinv[c]*( sum_{neighbors} H16[r] + H16[c] )
template <int F>
__global__ __launch_bounds__(256) void agg_half_kernel(const ushort* __restrict__ h,
                                                       const int* __restrict__ offs2,
                                                       const int* __restrict__ eidx,
                                                       const float* __restrict__ dinv,
                                                       const float* __restrict__ b,
                                                       float* __restrict__ out, int N) {
    constexpr int L = F / 8;
    int tid = blockIdx.x * 256 + threadIdx.x;
    int seg = tid / L;
    int jw  = tid % L;
    if (seg >= N) return;
    const uint4* hv = (const uint4*)h;

    float a0[8] = {}, a1[8] = {};
    const int base = seg * NBKT;
    int ks = offs2[base];
#pragma unroll
    for (int q = 0; q < NBKT; ++q) {
        int ke = offs2[base + q + 1];
        int k = ks;
        for (; k + 2 <= ke; k += 2) {
            int r0 = eidx[k], r1 = eidx[k + 1];
            h8acc(a0, hv[(size_t)r0 * L + jw]);
            h8acc(a1, hv[(size_t)r1 * L + jw]);
        }
        if (k < ke) h8acc(a0, hv[(size_t)eidx[k] * L + jw]);
        ks = ke;
    }
    h8acc(a0, hv[(size_t)seg * L + jw]);  // self-loop
#pragma unroll
    for (int i = 0; i < 8; ++i) a0[i] += a1[i];

    float  d  = dinv[seg];
    float4 b0 = *(const float4*)&b[jw * 8];
    float4 b1 = *(const float4*)&b[jw * 8 + 4];
    float4 o0 = {b0.x + d * a0[0], b0.y + d * a0[1], b0.z + d * a0[2], b0.w + d * a0[3]};
    float4 o1 = {b1.x + d * a0[4], b1.y + d * a0[5], b1.z + d * a0[6], b1.w + d * a0[7]};
    *(float4*)&out[(size_t)seg * F + jw * 8]     = o0;
    *(float4*)&out[(size_t)seg * F + jw * 8 + 4] = o1;
}

extern "C" void kernel_launch(void* const* d_in, const int* in_sizes, int n_in,
                              void* d_out, int out_size, void* d_ws, size_t ws_size,
                              hipStream_t stream) {
    const float* x  = (const float*)d_in[0];
    const int*   ei = (const int*)d_in[1];
    const float* W1 = (const float*)d_in[2];
    const float* b1 = (const float*)d_in[3];
    const float* W2 = (const float*)d_in[4];
    const float* b2 = (const float*)d_in[5];
    const float* W3 = (const float*)d_in[6];
    const float* b3 = (const float*)d_in[7];
    const float* W4 = (const float*)d_in[8];
    const float* b4 = (const float*)d_in[9];

    const int N = in_sizes[0] / 128;  // 100000
    const int E = in_sizes[1] / 2;    // 1600000
    const int* row = ei;              // source
    const int* col = ei + E;          // destination
    const int n2   = N * NBKT;
    const int span = (N + NBKT - 1) / NBKT;   // 12500
    const int nsb  = (span + SUBD - 1) / SUBD; // 98

    // ---- workspace layout ----------------------------------------------------
    // persistent: offs2, dinv, eidx, stag1, X(f32), H(fp16)
    // transient (alias X, dead before agg1 writes X): stag2, pcnt2, pcnt, sbase
    char* w = (char*)d_ws;
    int*      offs2 = (int*)w;               w += (size_t)(n2 + 4) * 4;
    float*    dinv  = (float*)w;             w += (size_t)N * 4;
    int*      eidx  = (int*)w;               w += (size_t)E * 4;
    unsigned* stag1 = (unsigned*)w;          w += (size_t)NBKT * CAP * 4;  // 8.4 MB
    float*    X     = (float*)w;             w += (size_t)N * 64 * 4;      // 25.6 MB
    ushort*   H     = (ushort*)w;                                          // 12.8 MB
    unsigned* stag2 = (unsigned*)X;                         // 12.85 MB into X
    int*      pcnt2 = (int*)(stag2 + (size_t)NBKT * nsb * CAP2);
    int*      pcnt  = pcnt2 + NBKT * nsb;
    int*      sbase = pcnt + NBKT;
    float*    out   = (float*)d_out;

    const int T  = 256;
    const int NB = (N + T - 1) / T;  // 391

    // ---- CSR build (coalesced-write counting sort) + norm ---------------------
    zero_i32_kernel<<<(NBKT * nsb + NBKT + T - 1) / T, T, 0, stream>>>(pcnt2, NBKT * nsb + NBKT);
    bin_kernel<<<1024, T, 0, stream>>>(row, col, pcnt, stag1, E, span);
    bin2_kernel<<<8 * (CAP / 4096), T, 0, stream>>>(stag1, pcnt, pcnt2, stag2, nsb);
    scan_small_kernel<<<1, 1024, 0, stream>>>(pcnt2, sbase, NBKT * nsb);
    sort_sub_kernel<<<8 * nsb, T, 0, stream>>>(stag2, pcnt2, sbase, offs2, eidx, span, nsb, E);
    dinv2_kernel<<<NB, T, 0, stream>>>(offs2, dinv, N);

    const int g64 = (N + 63) / 64;
    const int g32 = (N + 127) / 128;
    const int a64 = (N * 8 + T - 1) / T;
    const int a32 = (N * 4 + T - 1) / T;

    // ---- layer 1: x[128] -> 64 ------------------------------------------------
    gemm_tile_kernel<128, 64, false><<<g64, T, 0, stream>>>(x, W1, dinv, H, N);
    agg_half_kernel<64><<<a64, T, 0, stream>>>(H, offs2, eidx, dinv, b1, X, N);
    // ---- layer 2 ----------------------------------------------------------------
    gemm_tile_kernel<64, 64, true><<<g64, T, 0, stream>>>(X, W2, dinv, H, N);
    agg_half_kernel<64><<<a64, T, 0, stream>>>(H, offs2, eidx, dinv, b2, X, N);
    // ---- layer 3 ----------------------------------------------------------------
    gemm_tile_kernel<64, 64, true><<<g64, T, 0, stream>>>(X, W3, dinv, H, N);
    agg_half_kernel<64><<<a64, T, 0, stream>>>(H, offs2, eidx, dinv, b3, X, N);
    // ---- layer 4: 64 -> 32, no ReLU, straight to d_out --------------------------
    gemm_tile_kernel<64, 32, true><<<g32, T, 0, stream>>>(X, W4, dinv, H, N);
    agg_half_kernel<32><<<a32, T, 0, stream>>>(H, offs2, eidx, dinv, b4, out, N);
}